// Round 2
// baseline (2483.633 us; speedup 1.0000x reference)
//
#include <hip/hip_runtime.h>
#include <hip/hip_bf16.h>
#include <stdint.h>

// Graph_Refine: N=8192, D=128, E=262144, P=4, eps=0.3. All I/O fp32 (R1 finding:
// threshold == 2% * max|ref| exactly -> no bf16 floor -> fp32 harness dtypes).
#define N_NODES 8192
#define DIM     128
#define KTOT    512        // P*D concatenated perspectives
#define NEDGE   262144
#define EPS     0.3f
#define FIX_DELTA 0.02f    // > worst-case bf16-MFMA dot error (~0.008)
#define HASH_BITS 20
#define HASH_SLOTS (1u << HASH_BITS)
#define FIX_CAP (1u << 19)

typedef unsigned int u32;
typedef unsigned short u16;
typedef __attribute__((ext_vector_type(8))) short short8;   // bf16x8 MFMA frag
typedef __attribute__((ext_vector_type(4))) float float4v;

// workspace layout (bytes) — total 35.7 MB; zero-init region is one contiguous memset
#define OFF_YF 0u                    // fp32 Y [8192][512]   16 MB (exact recompute source)
#define OFF_YB 16777216u             // bf16 Y [8192][512]    8 MB (MFMA input)
#define OFF_FC 25165824u             // fixup count (256 B)
#define OFF_FL 25166080u             // fixup list u32[2^19]  2 MB
#define OFF_HK 27263232u             // hash keys u32[2^20]   4 MB
#define OFF_HV 31457536u             // hash vals f32[2^20]   4 MB
#define WS_END 35651840u
#define MEMSET_OFF OFF_FC
#define MEMSET_BYTES (WS_END - OFF_FC)

__device__ __forceinline__ u16 f2bf(float f) {  // RNE
    u32 b = __builtin_bit_cast(u32, f);
    b += 0x7fffu + ((b >> 16) & 1u);
    return (u16)(b >> 16);
}

// K1: per-node per-perspective reweight + L2-normalize; emit Y fp32 + bf16.
// One wave per node; lane holds d and d+64. 0.5 scale folds mean-over-P into Y.
__global__ void prep_y(const float* __restrict__ x, const float* __restrict__ wp,
                       float* __restrict__ yf, u16* __restrict__ yb) {
    int node = blockIdx.x * 4 + (threadIdx.x >> 6);
    int lane = threadIdx.x & 63;
    float x0 = x[node * DIM + lane];
    float x1 = x[node * DIM + lane + 64];
    for (int p = 0; p < 4; ++p) {
        float v0 = x0 * wp[p * DIM + lane];
        float v1 = x1 * wp[p * DIM + lane + 64];
        float ss = v0 * v0 + v1 * v1;
        #pragma unroll
        for (int o = 1; o < 64; o <<= 1) ss += __shfl_xor(ss, o, 64);
        float scale = 0.5f / fmaxf(sqrtf(ss), 1e-12f);
        float y0 = v0 * scale, y1 = v1 * scale;
        int base = node * KTOT + p * DIM;
        yf[base + lane] = y0;       yf[base + lane + 64] = y1;
        yb[base + lane] = f2bf(y0); yb[base + lane + 64] = f2bf(y1);
    }
}

// K2: aggregate duplicate edges: hash[cell] += w
__global__ void edge_insert(const int* __restrict__ idx, const float* __restrict__ w,
                            u32* __restrict__ hkey, float* __restrict__ hval) {
    int e = blockIdx.x * 256 + threadIdx.x;
    u32 cell = (u32)(idx[e] * N_NODES + idx[NEDGE + e]);
    float wv = w[e];
    u32 key = cell + 1u;
    u32 h = (cell * 2654435761u) >> (32 - HASH_BITS);
    while (true) {
        u32 old = atomicCAS(&hkey[h], 0u, key);
        if (old == 0u || old == key) { atomicAdd(&hval[h], wv); break; }
        h = (h + 1u) & (HASH_SLOTS - 1u);
    }
}

// K3: sim = Yb * Yb^T (bf16 MFMA), 128x128 tile, 4 waves 2x2, 64x64/wave.
#define TM  128
#define BK  64
#define LDK 72

__global__ __launch_bounds__(256)
void gemm_sim(const u16* __restrict__ yb, float* __restrict__ out,
              u32* __restrict__ fcnt, u32* __restrict__ flst) {
    __shared__ u16 As[TM * LDK];
    __shared__ u16 Bs[TM * LDK];
    int bm = blockIdx.y, bn = blockIdx.x;
    int tid = threadIdx.x;
    int lane = tid & 63, wid = tid >> 6;
    int wm = wid >> 1, wn = wid & 1;

    float4v acc[4][4] = {};
    const u16* arow = yb + (size_t)(bm * TM) * KTOT;
    const u16* brow = yb + (size_t)(bn * TM) * KTOT;

    for (int kt = 0; kt < KTOT / BK; ++kt) {
        __syncthreads();
        #pragma unroll
        for (int q = 0; q < 4; ++q) {
            int c = tid + q * 256;
            int row = c >> 3, kg = c & 7;
            *(uint4*)&As[row * LDK + kg * 8] = *(const uint4*)(arow + row * KTOT + kt * BK + kg * 8);
            *(uint4*)&Bs[row * LDK + kg * 8] = *(const uint4*)(brow + row * KTOT + kt * BK + kg * 8);
        }
        __syncthreads();
        #pragma unroll
        for (int kk = 0; kk < 2; ++kk) {
            short8 af[4], bfr[4];
            int kb = kk * 32 + (lane >> 4) * 8;
            int mrow = wm * 64 + (lane & 15);
            int ncol = wn * 64 + (lane & 15);
            #pragma unroll
            for (int i = 0; i < 4; ++i) {
                af[i]  = *(const short8*)&As[(mrow + i * 16) * LDK + kb];
                bfr[i] = *(const short8*)&Bs[(ncol + i * 16) * LDK + kb];
            }
            #pragma unroll
            for (int i = 0; i < 4; ++i)
                #pragma unroll
                for (int j = 0; j < 4; ++j)
                    acc[i][j] = __builtin_amdgcn_mfma_f32_16x16x32_bf16(
                        af[i], bfr[j], acc[i][j], 0, 0, 0);
        }
    }
    // C/D layout: col=lane&15, row=(lane>>4)*4+reg  [m89/m91]
    int quad = lane >> 4, lcol = lane & 15;
    #pragma unroll
    for (int i = 0; i < 4; ++i)
        #pragma unroll
        for (int j = 0; j < 4; ++j)
            #pragma unroll
            for (int r = 0; r < 4; ++r) {
                int row = bm * TM + wm * 64 + i * 16 + quad * 4 + r;
                int col = bn * TM + wn * 64 + j * 16 + lcol;
                float s = acc[i][j][r];
                out[(size_t)row * N_NODES + col] = s > EPS ? s : 0.f;
                if (fabsf(s - EPS) < FIX_DELTA) {  // bf16 can't decide -> exact fixup
                    u32 slot = atomicAdd(fcnt, 1u);
                    if (slot < FIX_CAP) flst[slot] = (u32)(row * N_NODES + col);
                }
            }
}

// exact fp32 dot of rows i,j of Y (16-lane team, coalesced float4)
__device__ __forceinline__ float dot_exact(const float* __restrict__ yf,
                                           u32 i, u32 j, int tl) {
    const float4v* ri = (const float4v*)(yf + (size_t)i * KTOT);
    const float4v* rj = (const float4v*)(yf + (size_t)j * KTOT);
    float4v p = {};
    #pragma unroll
    for (int q = 0; q < 8; ++q) p += ri[q * 16 + tl] * rj[q * 16 + tl];
    float s = p.x + p.y + p.z + p.w;
    #pragma unroll
    for (int o = 8; o >= 1; o >>= 1) s += __shfl_xor(s, o, 16);
    return s;
}

// K4: recompute near-threshold cells exactly in fp32
__global__ void fixup(const float* __restrict__ yf, const u32* __restrict__ fcnt,
                      const u32* __restrict__ flst, float* __restrict__ out) {
    u32 count = *fcnt; if (count > FIX_CAP) count = FIX_CAP;
    int team = (blockIdx.x * 256 + threadIdx.x) >> 4;
    int tl = threadIdx.x & 15;
    int nteams = gridDim.x * 16;
    for (u32 t = team; t < count; t += nteams) {
        u32 cell = flst[t];
        u32 i = cell >> 13, j = cell & 8191u;
        float s = dot_exact(yf, i, j, tl);
        if (tl == 0) out[cell] = s > EPS ? s : 0.f;
    }
}

// K5: per unique edge cell: out = sim_g + (sim*a > eps ? a : 0), exact fp32 sim
__global__ void edge_apply(const float* __restrict__ yf, const u32* __restrict__ hkey,
                           const float* __restrict__ hval, float* __restrict__ out) {
    int team = (blockIdx.x * 256 + threadIdx.x) >> 4;
    int tl = threadIdx.x & 15;
    int nteams = gridDim.x * 16;
    for (u32 slot = team; slot < HASH_SLOTS; slot += (u32)nteams) {
        u32 key = hkey[slot];
        if (!key) continue;
        u32 cell = key - 1u;
        float a = hval[slot];
        u32 i = cell >> 13, j = cell & 8191u;
        float s = dot_exact(yf, i, j, tl);
        if (tl == 0) {
            float sg = s > EPS ? s : 0.f;
            out[cell] = sg + ((s * a > EPS) ? a : 0.f);
        }
    }
}

extern "C" void kernel_launch(void* const* d_in, const int* in_sizes, int n_in,
                              void* d_out, int out_size, void* d_ws, size_t ws_size,
                              hipStream_t stream) {
    const float* x  = (const float*)d_in[0];
    const int*   oi = (const int*)d_in[1];
    const float* ow = (const float*)d_in[2];
    const float* wp = (const float*)d_in[3];
    float* out = (float*)d_out;
    char* ws = (char*)d_ws;
    float* yf = (float*)(ws + OFF_YF);
    u16*   yb = (u16*)(ws + OFF_YB);
    u32*   fc = (u32*)(ws + OFF_FC);
    u32*   fl = (u32*)(ws + OFF_FL);
    u32*   hk = (u32*)(ws + OFF_HK);
    float* hv = (float*)(ws + OFF_HV);

    prep_y<<<N_NODES / 4, 256, 0, stream>>>(x, wp, yf, yb);
    hipMemsetAsync(ws + MEMSET_OFF, 0, MEMSET_BYTES, stream);  // fc + fl + hash
    edge_insert<<<NEDGE / 256, 256, 0, stream>>>(oi, ow, hk, hv);
    gemm_sim<<<dim3(N_NODES / TM, N_NODES / TM), 256, 0, stream>>>(yb, out, fc, fl);
    fixup<<<2048, 256, 0, stream>>>(yf, fc, fl, out);
    edge_apply<<<2048, 256, 0, stream>>>(yf, hk, hv, out);
}

// Round 3
// 749.544 us; speedup vs baseline: 3.3135x; 3.3135x over previous
//
#include <hip/hip_runtime.h>
#include <hip/hip_bf16.h>
#include <stdint.h>

// Graph_Refine: N=8192, D=128, E=262144, P=4, eps=0.3. fp32 I/O.
// R3: (1) de-storm fixup atomics (LDS buffer, 1 global atomic/block)
//     (2) edge weights aggregated directly into out[] (RMW in gemm epilogue;
//         poison 0xAA = -3e-13 and memset-0 both excluded by a>0 guard)
//     (3) XOR-swizzled unpadded LDS tiles (2-way max bank aliasing = free)
#define N_NODES 8192
#define DIM     128
#define KTOT    512
#define NEDGE   262144
#define EPS     0.3f
#define FIX_DELTA 0.02f    // > worst-case bf16-MFMA dot error (~0.008)
#define FIX_CAP (1u << 19)
#define LCAP    1024

typedef unsigned int u32;
typedef unsigned short u16;
typedef unsigned long long u64;
typedef __attribute__((ext_vector_type(8))) short short8;
typedef __attribute__((ext_vector_type(4))) float float4v;

// workspace: YF 16MB | YB 8MB | FC 256B | FL 4MB  (total ~28.3 MB)
#define OFF_YF 0u
#define OFF_YB 16777216u
#define OFF_FC 25165824u
#define OFF_FL 25166080u

__device__ __forceinline__ u16 f2bf(float f) {  // RNE
    u32 b = __builtin_bit_cast(u32, f);
    b += 0x7fffu + ((b >> 16) & 1u);
    return (u16)(b >> 16);
}

// K1: reweight + L2-normalize per perspective; emit Y fp32 + bf16 (0.5 folds mean over P)
__global__ void prep_y(const float* __restrict__ x, const float* __restrict__ wp,
                       float* __restrict__ yf, u16* __restrict__ yb) {
    int node = blockIdx.x * 4 + (threadIdx.x >> 6);
    int lane = threadIdx.x & 63;
    float x0 = x[node * DIM + lane];
    float x1 = x[node * DIM + lane + 64];
    for (int p = 0; p < 4; ++p) {
        float v0 = x0 * wp[p * DIM + lane];
        float v1 = x1 * wp[p * DIM + lane + 64];
        float ss = v0 * v0 + v1 * v1;
        #pragma unroll
        for (int o = 1; o < 64; o <<= 1) ss += __shfl_xor(ss, o, 64);
        float scale = 0.5f / fmaxf(sqrtf(ss), 1e-12f);
        float y0 = v0 * scale, y1 = v1 * scale;
        int base = node * KTOT + p * DIM;
        yf[base + lane] = y0;       yf[base + lane + 64] = y1;
        yb[base + lane] = f2bf(y0); yb[base + lane + 64] = f2bf(y1);
    }
}

// K2a: zero edge cells (idempotent, covers duplicates)
__global__ void edge_zero(const int* __restrict__ idx, float* __restrict__ out) {
    int e = blockIdx.x * 256 + threadIdx.x;
    out[(size_t)idx[e] * N_NODES + idx[NEDGE + e]] = 0.f;
}
// K2b: aggregate duplicate edges into out
__global__ void edge_accum(const int* __restrict__ idx, const float* __restrict__ w,
                           float* __restrict__ out) {
    int e = blockIdx.x * 256 + threadIdx.x;
    atomicAdd(&out[(size_t)idx[e] * N_NODES + idx[NEDGE + e]], w[e]);
}

// K3: sim = Yb*Yb^T (bf16 MFMA), 128x128 tile, 4 waves 2x2, 64x64/wave.
// Epilogue: RMW edge purify + threshold + LDS-buffered fixup collection.
#define TM  128
#define BK  64

__global__ __launch_bounds__(256)
void gemm_sim(const u16* __restrict__ yb, float* __restrict__ out,
              u32* __restrict__ fcnt, u64* __restrict__ flst) {
    __shared__ u16 As[TM * BK];
    __shared__ u16 Bs[TM * BK];
    __shared__ u32 s_cnt, s_base;
    __shared__ u64 s_list[LCAP];
    int bm = blockIdx.y, bn = blockIdx.x;
    int tid = threadIdx.x;
    int lane = tid & 63, wid = tid >> 6;
    int wm = wid >> 1, wn = wid & 1;
    if (tid == 0) s_cnt = 0;

    float4v acc[4][4] = {};
    const u16* arow = yb + (size_t)(bm * TM) * KTOT;
    const u16* brow = yb + (size_t)(bn * TM) * KTOT;

    for (int kt = 0; kt < KTOT / BK; ++kt) {
        __syncthreads();
        #pragma unroll
        for (int q = 0; q < 4; ++q) {
            int c = tid + q * 256;              // 1024 chunks of 16B per tile
            int row = c >> 3, kg = c & 7;
            int sc = (kg ^ (row & 7)) * 8;      // XOR swizzle: write 2-way max
            *(uint4*)&As[row * BK + sc] = *(const uint4*)(arow + row * KTOT + kt * BK + kg * 8);
            *(uint4*)&Bs[row * BK + sc] = *(const uint4*)(brow + row * KTOT + kt * BK + kg * 8);
        }
        __syncthreads();
        #pragma unroll
        for (int kk = 0; kk < 2; ++kk) {
            short8 af[4], bfr[4];
            int kg2 = kk * 4 + (lane >> 4);     // which 8-elem K group
            int mrow = wm * 64 + (lane & 15);
            int ncol = wn * 64 + (lane & 15);
            #pragma unroll
            for (int i = 0; i < 4; ++i) {
                int ra = mrow + i * 16, rb = ncol + i * 16;
                af[i]  = *(const short8*)&As[ra * BK + ((kg2 ^ (ra & 7)) * 8)];
                bfr[i] = *(const short8*)&Bs[rb * BK + ((kg2 ^ (rb & 7)) * 8)];
            }
            #pragma unroll
            for (int i = 0; i < 4; ++i)
                #pragma unroll
                for (int j = 0; j < 4; ++j)
                    acc[i][j] = __builtin_amdgcn_mfma_f32_16x16x32_bf16(
                        af[i], bfr[j], acc[i][j], 0, 0, 0);
        }
    }
    // epilogue — C/D layout: col=lane&15, row=(lane>>4)*4+reg [m89/m91]
    int quad = lane >> 4, lcol = lane & 15;
    #pragma unroll
    for (int i = 0; i < 4; ++i)
        #pragma unroll
        for (int j = 0; j < 4; ++j) {
            int row0 = bm * TM + wm * 64 + i * 16 + quad * 4;
            int col  = bn * TM + wn * 64 + j * 16 + lcol;
            #pragma unroll
            for (int r = 0; r < 4; ++r) {
                u32 cell = (u32)((row0 + r) * N_NODES + col);
                float s = acc[i][j][r];
                float a = out[cell];            // edge Sum(w) if >0; poison/0 otherwise
                float v = s > EPS ? s : 0.f;
                bool flag = fabsf(s - EPS) < FIX_DELTA;
                if (a > 0.f) {
                    if (s * a > EPS) v += a;
                    flag |= fabsf(s * a - EPS) < a * FIX_DELTA;
                }
                out[cell] = v;
                if (flag) {                     // LDS-buffered; global atomic only on overflow
                    u64 ent = ((u64)__builtin_bit_cast(u32, a > 0.f ? a : 0.f) << 32) | cell;
                    u32 li = atomicAdd(&s_cnt, 1u);
                    if (li < LCAP) s_list[li] = ent;
                    else { u32 g = atomicAdd(fcnt, 1u); if (g < FIX_CAP) flst[g] = ent; }
                }
            }
        }
    __syncthreads();
    u32 cnt = s_cnt < LCAP ? s_cnt : LCAP;
    if (tid == 0) s_base = atomicAdd(fcnt, cnt);   // ONE global atomic per block
    __syncthreads();
    for (u32 t = tid; t < cnt; t += 256) {
        u32 g = s_base + t;
        if (g < FIX_CAP) flst[g] = s_list[t];
    }
}

// exact fp32 dot of rows i,j of Y (16-lane team)
__device__ __forceinline__ float dot_exact(const float* __restrict__ yf,
                                           u32 i, u32 j, int tl) {
    const float4v* ri = (const float4v*)(yf + (size_t)i * KTOT);
    const float4v* rj = (const float4v*)(yf + (size_t)j * KTOT);
    float4v p = {};
    #pragma unroll
    for (int q = 0; q < 8; ++q) p += ri[q * 16 + tl] * rj[q * 16 + tl];
    float s = p.x + p.y + p.z + p.w;
    #pragma unroll
    for (int o = 8; o >= 1; o >>= 1) s += __shfl_xor(s, o, 16);
    return s;
}

// K4: exact-fp32 recompute of knife-edge cells (incl. their edge term)
__global__ void fixup(const float* __restrict__ yf, const u32* __restrict__ fcnt,
                      const u64* __restrict__ flst, float* __restrict__ out) {
    u32 count = *fcnt; if (count > FIX_CAP) count = FIX_CAP;
    int team = (blockIdx.x * 256 + threadIdx.x) >> 4;
    int tl = threadIdx.x & 15;
    int nteams = gridDim.x * 16;
    for (u32 t = team; t < count; t += nteams) {
        u64 ent = flst[t];
        u32 cell = (u32)ent;
        float a = __builtin_bit_cast(float, (u32)(ent >> 32));
        u32 i = cell >> 13, j = cell & 8191u;
        float s = dot_exact(yf, i, j, tl);
        if (tl == 0) {
            float v = s > EPS ? s : 0.f;
            if (a > 0.f && s * a > EPS) v += a;
            out[cell] = v;
        }
    }
}

extern "C" void kernel_launch(void* const* d_in, const int* in_sizes, int n_in,
                              void* d_out, int out_size, void* d_ws, size_t ws_size,
                              hipStream_t stream) {
    const float* x  = (const float*)d_in[0];
    const int*   oi = (const int*)d_in[1];
    const float* ow = (const float*)d_in[2];
    const float* wp = (const float*)d_in[3];
    float* out = (float*)d_out;
    char* ws = (char*)d_ws;
    float* yf = (float*)(ws + OFF_YF);
    u16*   yb = (u16*)(ws + OFF_YB);
    u32*   fc = (u32*)(ws + OFF_FC);
    u64*   fl = (u64*)(ws + OFF_FL);

    prep_y<<<N_NODES / 4, 256, 0, stream>>>(x, wp, yf, yb);
    hipMemsetAsync(ws + OFF_FC, 0, 256, stream);
    edge_zero<<<NEDGE / 256, 256, 0, stream>>>(oi, out);
    edge_accum<<<NEDGE / 256, 256, 0, stream>>>(oi, ow, out);
    gemm_sim<<<dim3(N_NODES / TM, N_NODES / TM), 256, 0, stream>>>(yb, out, fc, fl);
    fixup<<<2048, 256, 0, stream>>>(yf, fc, fl, out);
}

// Round 4
// 729.150 us; speedup vs baseline: 3.4062x; 1.0280x over previous
//
#include <hip/hip_runtime.h>
#include <hip/hip_bf16.h>
#include <stdint.h>

// Graph_Refine: N=8192, D=128, E=262144, P=4, eps=0.3. fp32 I/O.
// R4: (1) global_load_lds width-16 staging (m97 ladder step, fixes latency-bound
//         K-loop seen in R3: all pipes <15%)
//     (2) symmetric gram: compute bm<=bn tiles only, mirrored float4 store
//     (3) LCAP 512 -> 36.9 KB LDS -> 4 blocks/CU
#define N_NODES 8192
#define DIM     128
#define KTOT    512
#define NEDGE   262144
#define EPS     0.3f
#define FIX_DELTA 0.02f    // > worst-case bf16-MFMA dot error (~0.008)
#define FIX_CAP (1u << 19)
#define LCAP    512

typedef unsigned int u32;
typedef unsigned short u16;
typedef unsigned long long u64;
typedef __attribute__((ext_vector_type(8))) short short8;
typedef __attribute__((ext_vector_type(4))) float float4v;

// workspace: YF 16MB | YB 8MB | FC 256B | FL 4MB
#define OFF_YF 0u
#define OFF_YB 16777216u
#define OFF_FC 25165824u
#define OFF_FL 25166080u

__device__ __forceinline__ u16 f2bf(float f) {  // RNE
    u32 b = __builtin_bit_cast(u32, f);
    b += 0x7fffu + ((b >> 16) & 1u);
    return (u16)(b >> 16);
}

// K1: reweight + L2-normalize per perspective; emit Y fp32 + bf16 (0.5 folds mean over P)
__global__ void prep_y(const float* __restrict__ x, const float* __restrict__ wp,
                       float* __restrict__ yf, u16* __restrict__ yb) {
    int node = blockIdx.x * 4 + (threadIdx.x >> 6);
    int lane = threadIdx.x & 63;
    float x0 = x[node * DIM + lane];
    float x1 = x[node * DIM + lane + 64];
    for (int p = 0; p < 4; ++p) {
        float v0 = x0 * wp[p * DIM + lane];
        float v1 = x1 * wp[p * DIM + lane + 64];
        float ss = v0 * v0 + v1 * v1;
        #pragma unroll
        for (int o = 1; o < 64; o <<= 1) ss += __shfl_xor(ss, o, 64);
        float scale = 0.5f / fmaxf(sqrtf(ss), 1e-12f);
        float y0 = v0 * scale, y1 = v1 * scale;
        int base = node * KTOT + p * DIM;
        yf[base + lane] = y0;       yf[base + lane + 64] = y1;
        yb[base + lane] = f2bf(y0); yb[base + lane + 64] = f2bf(y1);
    }
}

// K2a: zero edge cells (idempotent, covers duplicates)
__global__ void edge_zero(const int* __restrict__ idx, float* __restrict__ out) {
    int e = blockIdx.x * 256 + threadIdx.x;
    out[(size_t)idx[e] * N_NODES + idx[NEDGE + e]] = 0.f;
}
// K2b: aggregate duplicate edges into out
__global__ void edge_accum(const int* __restrict__ idx, const float* __restrict__ w,
                           float* __restrict__ out) {
    int e = blockIdx.x * 256 + threadIdx.x;
    atomicAdd(&out[(size_t)idx[e] * N_NODES + idx[NEDGE + e]], w[e]);
}

// K3: sim = Yb*Yb^T, upper-triangle tiles only; glds staging; RMW purify epilogue.
#define TM  128
#define BK  64

__global__ __launch_bounds__(256)
void gemm_sim(const u16* __restrict__ yb, float* __restrict__ out,
              u32* __restrict__ fcnt, u64* __restrict__ flst) {
    int bm = blockIdx.y, bn = blockIdx.x;
    if (bm > bn) return;                        // symmetric: upper triangle only
    __shared__ __align__(16) u16 As[TM * BK];
    __shared__ __align__(16) u16 Bs[TM * BK];
    __shared__ u32 s_cnt, s_base;
    __shared__ u64 s_list[LCAP];
    int tid = threadIdx.x;
    int lane = tid & 63, wid = tid >> 6;
    int wm = wid >> 1, wn = wid & 1;
    if (tid == 0) s_cnt = 0;

    float4v acc[4][4] = {};
    const u16* arow = yb + (size_t)(bm * TM) * KTOT;
    const u16* brow = yb + (size_t)(bn * TM) * KTOT;

    for (int kt = 0; kt < KTOT / BK; ++kt) {
        __syncthreads();                        // prev iter's ds_reads done
        #pragma unroll
        for (int q = 0; q < 4; ++q) {
            int c = q * 256 + wid * 64 + lane;  // 16B chunk id; row=c>>3, kg=c&7
            int row = c >> 3, kg = c & 7;
            // LDS dest: wave-uniform base + lane*16 (glds constraint) -> [row][64] layout
            __builtin_amdgcn_global_load_lds(
                (const __attribute__((address_space(1))) void*)(const void*)(arow + (size_t)row * KTOT + kt * BK + kg * 8),
                (__attribute__((address_space(3))) void*)(void*)(As + (q * 256 + wid * 64) * 8),
                16, 0, 0);
            __builtin_amdgcn_global_load_lds(
                (const __attribute__((address_space(1))) void*)(const void*)(brow + (size_t)row * KTOT + kt * BK + kg * 8),
                (__attribute__((address_space(3))) void*)(void*)(Bs + (q * 256 + wid * 64) * 8),
                16, 0, 0);
        }
        __syncthreads();                        // drains vmcnt (glds) + LDS visible
        #pragma unroll
        for (int kk = 0; kk < 2; ++kk) {
            short8 af[4], bfr[4];
            int kb = kk * 32 + (lane >> 4) * 8; // u16 index within row
            int mrow = wm * 64 + (lane & 15);
            int ncol = wn * 64 + (lane & 15);
            #pragma unroll
            for (int i = 0; i < 4; ++i) {
                af[i]  = *(const short8*)&As[(mrow + i * 16) * BK + kb];
                bfr[i] = *(const short8*)&Bs[(ncol + i * 16) * BK + kb];
            }
            #pragma unroll
            for (int i = 0; i < 4; ++i)
                #pragma unroll
                for (int j = 0; j < 4; ++j)
                    acc[i][j] = __builtin_amdgcn_mfma_f32_16x16x32_bf16(
                        af[i], bfr[j], acc[i][j], 0, 0, 0);
        }
    }

    // epilogue — C/D layout: col=lane&15, row=(lane>>4)*4+reg [m89/m91]
    int quad = lane >> 4, lcol = lane & 15;
    bool diag = (bm == bn);
    #pragma unroll
    for (int i = 0; i < 4; ++i)
        #pragma unroll
        for (int j = 0; j < 4; ++j) {
            int gr0 = bm * TM + wm * 64 + i * 16 + quad * 4;
            int gc  = bn * TM + wn * 64 + j * 16 + lcol;
            float4v v = acc[i][j];
            #pragma unroll
            for (int r = 0; r < 4; ++r) {       // direct tile (coalesced per quad)
                u32 cell = (u32)((gr0 + r) * N_NODES + gc);
                float s = v[r];
                float a = out[cell];            // edge Sum(w) if >0; poison/0 else
                float o = s > EPS ? s : 0.f;
                bool flag = fabsf(s - EPS) < FIX_DELTA;
                if (a > 0.f) {
                    if (s * a > EPS) o += a;
                    flag |= fabsf(s * a - EPS) < a * FIX_DELTA;
                }
                out[cell] = o;
                if (flag) {
                    u64 ent = ((u64)__builtin_bit_cast(u32, a > 0.f ? a : 0.f) << 32) | cell;
                    u32 li = atomicAdd(&s_cnt, 1u);
                    if (li < LCAP) s_list[li] = ent;
                    else { u32 g = atomicAdd(fcnt, 1u); if (g < FIX_CAP) flst[g] = ent; }
                }
            }
            if (!diag) {                        // mirrored tile: float4 RMW per lane
                size_t tb = (size_t)gc * N_NODES + gr0;
                float4v at = *(float4v*)&out[tb];
                float4v ov;
                #pragma unroll
                for (int r = 0; r < 4; ++r) {
                    float s = v[r];             // sim(gc, gr0+r) == sim(gr0+r, gc)
                    float a = at[r];
                    float o = s > EPS ? s : 0.f;
                    bool flag = fabsf(s - EPS) < FIX_DELTA;
                    if (a > 0.f) {
                        if (s * a > EPS) o += a;
                        flag |= fabsf(s * a - EPS) < a * FIX_DELTA;
                    }
                    ov[r] = o;
                    if (flag) {
                        u32 cell = (u32)(tb + r);
                        u64 ent = ((u64)__builtin_bit_cast(u32, a > 0.f ? a : 0.f) << 32) | cell;
                        u32 li = atomicAdd(&s_cnt, 1u);
                        if (li < LCAP) s_list[li] = ent;
                        else { u32 g = atomicAdd(fcnt, 1u); if (g < FIX_CAP) flst[g] = ent; }
                    }
                }
                *(float4v*)&out[tb] = ov;
            }
        }
    __syncthreads();
    u32 cnt = s_cnt < LCAP ? s_cnt : LCAP;
    if (tid == 0) s_base = atomicAdd(fcnt, cnt);   // ONE global atomic per block
    __syncthreads();
    for (u32 t = tid; t < cnt; t += 256) {
        u32 g = s_base + t;
        if (g < FIX_CAP) flst[g] = s_list[t];
    }
}

// exact fp32 dot of rows i,j of Y (16-lane team)
__device__ __forceinline__ float dot_exact(const float* __restrict__ yf,
                                           u32 i, u32 j, int tl) {
    const float4v* ri = (const float4v*)(yf + (size_t)i * KTOT);
    const float4v* rj = (const float4v*)(yf + (size_t)j * KTOT);
    float4v p = {};
    #pragma unroll
    for (int q = 0; q < 8; ++q) p += ri[q * 16 + tl] * rj[q * 16 + tl];
    float s = p.x + p.y + p.z + p.w;
    #pragma unroll
    for (int o = 8; o >= 1; o >>= 1) s += __shfl_xor(s, o, 16);
    return s;
}

// K4: exact-fp32 recompute of knife-edge cells (incl. their edge term)
__global__ void fixup(const float* __restrict__ yf, const u32* __restrict__ fcnt,
                      const u64* __restrict__ flst, float* __restrict__ out) {
    u32 count = *fcnt; if (count > FIX_CAP) count = FIX_CAP;
    int team = (blockIdx.x * 256 + threadIdx.x) >> 4;
    int tl = threadIdx.x & 15;
    int nteams = gridDim.x * 16;
    for (u32 t = team; t < count; t += nteams) {
        u64 ent = flst[t];
        u32 cell = (u32)ent;
        float a = __builtin_bit_cast(float, (u32)(ent >> 32));
        u32 i = cell >> 13, j = cell & 8191u;
        float s = dot_exact(yf, i, j, tl);
        if (tl == 0) {
            float v = s > EPS ? s : 0.f;
            if (a > 0.f && s * a > EPS) v += a;
            out[cell] = v;
        }
    }
}

extern "C" void kernel_launch(void* const* d_in, const int* in_sizes, int n_in,
                              void* d_out, int out_size, void* d_ws, size_t ws_size,
                              hipStream_t stream) {
    const float* x  = (const float*)d_in[0];
    const int*   oi = (const int*)d_in[1];
    const float* ow = (const float*)d_in[2];
    const float* wp = (const float*)d_in[3];
    float* out = (float*)d_out;
    char* ws = (char*)d_ws;
    float* yf = (float*)(ws + OFF_YF);
    u16*   yb = (u16*)(ws + OFF_YB);
    u32*   fc = (u32*)(ws + OFF_FC);
    u64*   fl = (u64*)(ws + OFF_FL);

    prep_y<<<N_NODES / 4, 256, 0, stream>>>(x, wp, yf, yb);
    hipMemsetAsync(ws + OFF_FC, 0, 256, stream);
    edge_zero<<<NEDGE / 256, 256, 0, stream>>>(oi, out);
    edge_accum<<<NEDGE / 256, 256, 0, stream>>>(oi, ow, out);
    gemm_sim<<<dim3(N_NODES / TM, N_NODES / TM), 256, 0, stream>>>(yb, out, fc, fl);
    fixup<<<2048, 256, 0, stream>>>(yf, fc, fl, out);
}

// Round 5
// 655.930 us; speedup vs baseline: 3.7864x; 1.1116x over previous
//
#include <hip/hip_runtime.h>
#include <hip/hip_bf16.h>
#include <stdint.h>

// Graph_Refine: N=8192, D=128, E=262144, P=4, eps=0.3. fp32 I/O.
// R5: R3/R4 showed gemm pinned at 414us by the out[] RMW epilogue (identical dur
// with half the MFMA). Fix: pure streaming-store epilogue (no out reads); edges
// via hash + compact unique list, recomputed exactly post-gemm; glds staging with
// SOURCE-side XOR swizzle (LDS stays lane-contiguous, ds_reads conflict-free).
#define N_NODES 8192
#define DIM     128
#define KTOT    512
#define NEDGE   262144
#define EPS     0.3f
#define FIX_DELTA 0.02f    // > worst-case bf16-MFMA dot error (~0.008)
#define FIX_CAP (1u << 19)
#define LCAP    512
#define HASH_BITS 19
#define HASH_SLOTS (1u << HASH_BITS)

typedef unsigned int u32;
typedef unsigned short u16;
typedef __attribute__((ext_vector_type(8))) short short8;
typedef __attribute__((ext_vector_type(4))) float float4v;

// workspace layout (bytes) — 32.5 MB total (<= 35.65 MB proven in R2)
#define OFF_YF 0u            // fp32 Y [8192][512] 16 MB
#define OFF_YB 16777216u     // bf16 Y  8 MB
#define OFF_FC 25165824u     // fixup count
#define OFF_UC 25166080u     // unique-edge count
#define OFF_HK 25166336u     // hash keys u32[2^19] 2 MB
#define OFF_HV 27263488u     // hash vals f32[2^19] 2 MB
#define OFF_FL 29360640u     // fixup list u32[2^19] 2 MB
#define OFF_UL 31457792u     // unique list u32[NEDGE] 1 MB
#define MEMSET_OFF OFF_FC
#define MEMSET_BYTES (OFF_FL - OFF_FC)   // fc+uc+hash

__device__ __forceinline__ u16 f2bf(float f) {  // RNE
    u32 b = __builtin_bit_cast(u32, f);
    b += 0x7fffu + ((b >> 16) & 1u);
    return (u16)(b >> 16);
}

// K1: reweight + L2-normalize per perspective; emit Y fp32 + bf16 (0.5 folds mean over P)
__global__ void prep_y(const float* __restrict__ x, const float* __restrict__ wp,
                       float* __restrict__ yf, u16* __restrict__ yb) {
    int node = blockIdx.x * 4 + (threadIdx.x >> 6);
    int lane = threadIdx.x & 63;
    float x0 = x[node * DIM + lane];
    float x1 = x[node * DIM + lane + 64];
    for (int p = 0; p < 4; ++p) {
        float v0 = x0 * wp[p * DIM + lane];
        float v1 = x1 * wp[p * DIM + lane + 64];
        float ss = v0 * v0 + v1 * v1;
        #pragma unroll
        for (int o = 1; o < 64; o <<= 1) ss += __shfl_xor(ss, o, 64);
        float scale = 0.5f / fmaxf(sqrtf(ss), 1e-12f);
        float y0 = v0 * scale, y1 = v1 * scale;
        int base = node * KTOT + p * DIM;
        yf[base + lane] = y0;       yf[base + lane + 64] = y1;
        yb[base + lane] = f2bf(y0); yb[base + lane + 64] = f2bf(y1);
    }
}

// K2: hash-aggregate duplicate edges + compact unique-slot list
__global__ void edge_insert(const int* __restrict__ idx, const float* __restrict__ w,
                            u32* __restrict__ hkey, float* __restrict__ hval,
                            u32* __restrict__ ucnt, u32* __restrict__ ulist) {
    int e = blockIdx.x * 256 + threadIdx.x;
    u32 cell = (u32)(idx[e] * N_NODES + idx[NEDGE + e]);
    float wv = w[e];
    u32 key = cell + 1u;
    u32 h = (cell * 2654435761u) >> (32 - HASH_BITS);
    while (true) {
        u32 old = atomicCAS(&hkey[h], 0u, key);
        if (old == 0u) { ulist[atomicAdd(ucnt, 1u)] = h; atomicAdd(&hval[h], wv); break; }
        if (old == key) { atomicAdd(&hval[h], wv); break; }
        h = (h + 1u) & (HASH_SLOTS - 1u);
    }
}

// K3: sim = Yb*Yb^T, full grid, glds staging (source-swizzled), pure-store epilogue.
#define TM  128
#define BK  64

__global__ __launch_bounds__(256)
void gemm_sim(const u16* __restrict__ yb, float* __restrict__ out,
              u32* __restrict__ fcnt, u32* __restrict__ flst) {
    __shared__ __align__(16) u16 As[TM * BK];
    __shared__ __align__(16) u16 Bs[TM * BK];
    __shared__ u32 s_cnt, s_base;
    __shared__ u32 s_list[LCAP];
    int bm = blockIdx.y, bn = blockIdx.x;
    int tid = threadIdx.x;
    int lane = tid & 63, wid = tid >> 6;
    int wm = wid >> 1, wn = wid & 1;
    if (tid == 0) s_cnt = 0;

    float4v acc[4][4] = {};
    const u16* arow = yb + (size_t)(bm * TM) * KTOT;
    const u16* brow = yb + (size_t)(bn * TM) * KTOT;

    for (int kt = 0; kt < KTOT / BK; ++kt) {
        __syncthreads();                        // prev iter's ds_reads done
        #pragma unroll
        for (int q = 0; q < 4; ++q) {
            int c = q * 256 + wid * 64 + lane;  // LDS chunk slot (16B units)
            int row = c >> 3;
            int kg = (c & 7) ^ (row & 7);       // source-side XOR swizzle
            __builtin_amdgcn_global_load_lds(
                (const __attribute__((address_space(1))) void*)(const void*)(arow + (size_t)row * KTOT + kt * BK + kg * 8),
                (__attribute__((address_space(3))) void*)(void*)(As + (q * 256 + wid * 64) * 8),
                16, 0, 0);
            __builtin_amdgcn_global_load_lds(
                (const __attribute__((address_space(1))) void*)(const void*)(brow + (size_t)row * KTOT + kt * BK + kg * 8),
                (__attribute__((address_space(3))) void*)(void*)(Bs + (q * 256 + wid * 64) * 8),
                16, 0, 0);
        }
        __syncthreads();                        // drains vmcnt (glds)
        #pragma unroll
        for (int kk = 0; kk < 2; ++kk) {
            short8 af[4], bfr[4];
            int kg2 = kk * 4 + (lane >> 4);     // 8-elem K group index
            int mrow = wm * 64 + (lane & 15);
            int ncol = wn * 64 + (lane & 15);
            #pragma unroll
            for (int i = 0; i < 4; ++i) {
                int ra = mrow + i * 16, rb = ncol + i * 16;
                af[i]  = *(const short8*)&As[ra * BK + ((kg2 ^ (ra & 7)) * 8)];
                bfr[i] = *(const short8*)&Bs[rb * BK + ((kg2 ^ (rb & 7)) * 8)];
            }
            #pragma unroll
            for (int i = 0; i < 4; ++i)
                #pragma unroll
                for (int j = 0; j < 4; ++j)
                    acc[i][j] = __builtin_amdgcn_mfma_f32_16x16x32_bf16(
                        af[i], bfr[j], acc[i][j], 0, 0, 0);
        }
    }

    // epilogue — pure streaming store. C/D layout: col=lane&15, row=quad*4+r [m89/m91]
    int quad = lane >> 4, lcol = lane & 15;
    #pragma unroll
    for (int i = 0; i < 4; ++i)
        #pragma unroll
        for (int j = 0; j < 4; ++j) {
            int gr0 = bm * TM + wm * 64 + i * 16 + quad * 4;
            int gc  = bn * TM + wn * 64 + j * 16 + lcol;
            #pragma unroll
            for (int r = 0; r < 4; ++r) {
                float s = acc[i][j][r];
                out[(size_t)(gr0 + r) * N_NODES + gc] = s > EPS ? s : 0.f;
                if (fabsf(s - EPS) < FIX_DELTA) {
                    u32 li = atomicAdd(&s_cnt, 1u);
                    u32 cell = (u32)((gr0 + r) * N_NODES + gc);
                    if (li < LCAP) s_list[li] = cell;
                    else { u32 g = atomicAdd(fcnt, 1u); if (g < FIX_CAP) flst[g] = cell; }
                }
            }
        }
    __syncthreads();
    u32 cnt = s_cnt < LCAP ? s_cnt : LCAP;
    if (tid == 0) s_base = atomicAdd(fcnt, cnt);   // ONE global atomic per block
    __syncthreads();
    for (u32 t = tid; t < cnt; t += 256) {
        u32 g = s_base + t;
        if (g < FIX_CAP) flst[g] = s_list[t];
    }
}

// exact fp32 dot of rows i,j of Y (16-lane team)
__device__ __forceinline__ float dot_exact(const float* __restrict__ yf,
                                           u32 i, u32 j, int tl) {
    const float4v* ri = (const float4v*)(yf + (size_t)i * KTOT);
    const float4v* rj = (const float4v*)(yf + (size_t)j * KTOT);
    float4v p = {};
    #pragma unroll
    for (int q = 0; q < 8; ++q) p += ri[q * 16 + tl] * rj[q * 16 + tl];
    float s = p.x + p.y + p.z + p.w;
    #pragma unroll
    for (int o = 8; o >= 1; o >>= 1) s += __shfl_xor(s, o, 16);
    return s;
}

// K4: exact recompute of knife-edge sim cells (edge cells fixed later by edge_apply)
__global__ void fixup(const float* __restrict__ yf, const u32* __restrict__ fcnt,
                      const u32* __restrict__ flst, float* __restrict__ out) {
    u32 count = *fcnt; if (count > FIX_CAP) count = FIX_CAP;
    int team = (blockIdx.x * 256 + threadIdx.x) >> 4;
    int tl = threadIdx.x & 15;
    int nteams = gridDim.x * 16;
    for (u32 t = team; t < count; t += nteams) {
        u32 cell = flst[t];
        u32 i = cell >> 13, j = cell & 8191u;
        float s = dot_exact(yf, i, j, tl);
        if (tl == 0) out[cell] = s > EPS ? s : 0.f;
    }
}

// K5: per unique edge cell, exact final value = sim_g + (s*a>eps ? a : 0). Overwrites.
__global__ void edge_apply(const float* __restrict__ yf, const u32* __restrict__ hkey,
                           const float* __restrict__ hval, const u32* __restrict__ ucnt,
                           const u32* __restrict__ ulist, float* __restrict__ out) {
    u32 count = *ucnt;
    int team = (blockIdx.x * 256 + threadIdx.x) >> 4;
    int tl = threadIdx.x & 15;
    int nteams = gridDim.x * 16;
    for (u32 t = team; t < count; t += nteams) {
        u32 h = ulist[t];
        u32 cell = hkey[h] - 1u;
        float a = hval[h];
        u32 i = cell >> 13, j = cell & 8191u;
        float s = dot_exact(yf, i, j, tl);
        if (tl == 0) {
            float v = s > EPS ? s : 0.f;
            if (s * a > EPS) v += a;
            out[cell] = v;
        }
    }
}

extern "C" void kernel_launch(void* const* d_in, const int* in_sizes, int n_in,
                              void* d_out, int out_size, void* d_ws, size_t ws_size,
                              hipStream_t stream) {
    const float* x  = (const float*)d_in[0];
    const int*   oi = (const int*)d_in[1];
    const float* ow = (const float*)d_in[2];
    const float* wp = (const float*)d_in[3];
    float* out = (float*)d_out;
    char* ws = (char*)d_ws;
    float* yf = (float*)(ws + OFF_YF);
    u16*   yb = (u16*)(ws + OFF_YB);
    u32*   fc = (u32*)(ws + OFF_FC);
    u32*   uc = (u32*)(ws + OFF_UC);
    u32*   hk = (u32*)(ws + OFF_HK);
    float* hv = (float*)(ws + OFF_HV);
    u32*   fl = (u32*)(ws + OFF_FL);
    u32*   ul = (u32*)(ws + OFF_UL);

    prep_y<<<N_NODES / 4, 256, 0, stream>>>(x, wp, yf, yb);
    hipMemsetAsync(ws + MEMSET_OFF, 0, MEMSET_BYTES, stream);  // fc+uc+hash
    edge_insert<<<NEDGE / 256, 256, 0, stream>>>(oi, ow, hk, hv, uc, ul);
    gemm_sim<<<dim3(N_NODES / TM, N_NODES / TM), 256, 0, stream>>>(yb, out, fc, fl);
    fixup<<<2048, 256, 0, stream>>>(yf, fc, fl, out);
    edge_apply<<<2048, 256, 0, stream>>>(yf, hk, hv, uc, ul, out);
}

// Round 6
// 526.159 us; speedup vs baseline: 4.7203x; 1.2466x over previous
//
#include <hip/hip_runtime.h>
#include <hip/hip_bf16.h>
#include <stdint.h>

// Graph_Refine: N=8192, D=128, E=262144, P=4, eps=0.3. fp32 I/O.
// R6: edge_apply's 260k exact dots (1 GB L3 reads, ~140us) replaced by O(1)/cell
// reuse of gemm's stored sim (decision-exact after fixup); exact-dot fallback only
// for a>1 / knife-edge cells (~3k). FIX_DELTA 0.02->0.008 (observed dot err
// 0.00195 max over 4x67M cells; 4x margin) -> fixup traffic halved.
// Harness floor identified in R5: 1GiB ws-poison fill (211us) + out-poison (~53us).
#define N_NODES 8192
#define DIM     128
#define KTOT    512
#define NEDGE   262144
#define EPS     0.3f
#define FIX_DELTA 0.008f
#define FIX_CAP (1u << 19)
#define XCAP    (1u << 18)
#define LCAP    512
#define HASH_BITS 19
#define HASH_SLOTS (1u << HASH_BITS)

typedef unsigned int u32;
typedef unsigned short u16;
typedef __attribute__((ext_vector_type(8))) short short8;
typedef __attribute__((ext_vector_type(4))) float float4v;

// workspace layout (bytes)
#define OFF_YF  0u           // fp32 Y [8192][512] 16 MB
#define OFF_YB  16777216u    // bf16 Y  8 MB
#define OFF_CTR 25165824u    // counters: fc@0, uc@4, xc@8 (256 B)
#define OFF_HK  25166080u    // hash keys u32[2^19] 2 MB
#define OFF_HV  27263232u    // hash vals f32[2^19] 2 MB
#define OFF_FL  29360384u    // fixup list u32 2 MB
#define OFF_UL  31457536u    // unique list u32 1 MB
#define OFF_XL  32506112u    // exact-fallback list (hash slot) u32 1 MB
#define MEMSET_OFF OFF_CTR
#define MEMSET_BYTES (OFF_FL - OFF_CTR)   // counters + hk + hv

__device__ __forceinline__ u16 f2bf(float f) {  // RNE
    u32 b = __builtin_bit_cast(u32, f);
    b += 0x7fffu + ((b >> 16) & 1u);
    return (u16)(b >> 16);
}

// K1: reweight + L2-normalize per perspective; emit Y fp32 + bf16 (0.5 folds mean over P)
__global__ void prep_y(const float* __restrict__ x, const float* __restrict__ wp,
                       float* __restrict__ yf, u16* __restrict__ yb) {
    int node = blockIdx.x * 4 + (threadIdx.x >> 6);
    int lane = threadIdx.x & 63;
    float x0 = x[node * DIM + lane];
    float x1 = x[node * DIM + lane + 64];
    for (int p = 0; p < 4; ++p) {
        float v0 = x0 * wp[p * DIM + lane];
        float v1 = x1 * wp[p * DIM + lane + 64];
        float ss = v0 * v0 + v1 * v1;
        #pragma unroll
        for (int o = 1; o < 64; o <<= 1) ss += __shfl_xor(ss, o, 64);
        float scale = 0.5f / fmaxf(sqrtf(ss), 1e-12f);
        float y0 = v0 * scale, y1 = v1 * scale;
        int base = node * KTOT + p * DIM;
        yf[base + lane] = y0;       yf[base + lane + 64] = y1;
        yb[base + lane] = f2bf(y0); yb[base + lane + 64] = f2bf(y1);
    }
}

// K2: hash-aggregate duplicate edges + compact unique-slot list
__global__ void edge_insert(const int* __restrict__ idx, const float* __restrict__ w,
                            u32* __restrict__ hkey, float* __restrict__ hval,
                            u32* __restrict__ ucnt, u32* __restrict__ ulist) {
    int e = blockIdx.x * 256 + threadIdx.x;
    u32 cell = (u32)(idx[e] * N_NODES + idx[NEDGE + e]);
    float wv = w[e];
    u32 key = cell + 1u;
    u32 h = (cell * 2654435761u) >> (32 - HASH_BITS);
    while (true) {
        u32 old = atomicCAS(&hkey[h], 0u, key);
        if (old == 0u) { ulist[atomicAdd(ucnt, 1u)] = h; atomicAdd(&hval[h], wv); break; }
        if (old == key) { atomicAdd(&hval[h], wv); break; }
        h = (h + 1u) & (HASH_SLOTS - 1u);
    }
}

// K3: sim = Yb*Yb^T, glds staging (source-swizzled), pure-store epilogue. (unchanged R5)
#define TM  128
#define BK  64

__global__ __launch_bounds__(256)
void gemm_sim(const u16* __restrict__ yb, float* __restrict__ out,
              u32* __restrict__ fcnt, u32* __restrict__ flst) {
    __shared__ __align__(16) u16 As[TM * BK];
    __shared__ __align__(16) u16 Bs[TM * BK];
    __shared__ u32 s_cnt, s_base;
    __shared__ u32 s_list[LCAP];
    int bm = blockIdx.y, bn = blockIdx.x;
    int tid = threadIdx.x;
    int lane = tid & 63, wid = tid >> 6;
    int wm = wid >> 1, wn = wid & 1;
    if (tid == 0) s_cnt = 0;

    float4v acc[4][4] = {};
    const u16* arow = yb + (size_t)(bm * TM) * KTOT;
    const u16* brow = yb + (size_t)(bn * TM) * KTOT;

    for (int kt = 0; kt < KTOT / BK; ++kt) {
        __syncthreads();
        #pragma unroll
        for (int q = 0; q < 4; ++q) {
            int c = q * 256 + wid * 64 + lane;
            int row = c >> 3;
            int kg = (c & 7) ^ (row & 7);       // source-side XOR swizzle
            __builtin_amdgcn_global_load_lds(
                (const __attribute__((address_space(1))) void*)(const void*)(arow + (size_t)row * KTOT + kt * BK + kg * 8),
                (__attribute__((address_space(3))) void*)(void*)(As + (q * 256 + wid * 64) * 8),
                16, 0, 0);
            __builtin_amdgcn_global_load_lds(
                (const __attribute__((address_space(1))) void*)(const void*)(brow + (size_t)row * KTOT + kt * BK + kg * 8),
                (__attribute__((address_space(3))) void*)(void*)(Bs + (q * 256 + wid * 64) * 8),
                16, 0, 0);
        }
        __syncthreads();
        #pragma unroll
        for (int kk = 0; kk < 2; ++kk) {
            short8 af[4], bfr[4];
            int kg2 = kk * 4 + (lane >> 4);
            int mrow = wm * 64 + (lane & 15);
            int ncol = wn * 64 + (lane & 15);
            #pragma unroll
            for (int i = 0; i < 4; ++i) {
                int ra = mrow + i * 16, rb = ncol + i * 16;
                af[i]  = *(const short8*)&As[ra * BK + ((kg2 ^ (ra & 7)) * 8)];
                bfr[i] = *(const short8*)&Bs[rb * BK + ((kg2 ^ (rb & 7)) * 8)];
            }
            #pragma unroll
            for (int i = 0; i < 4; ++i)
                #pragma unroll
                for (int j = 0; j < 4; ++j)
                    acc[i][j] = __builtin_amdgcn_mfma_f32_16x16x32_bf16(
                        af[i], bfr[j], acc[i][j], 0, 0, 0);
        }
    }

    int quad = lane >> 4, lcol = lane & 15;
    #pragma unroll
    for (int i = 0; i < 4; ++i)
        #pragma unroll
        for (int j = 0; j < 4; ++j) {
            int gr0 = bm * TM + wm * 64 + i * 16 + quad * 4;
            int gc  = bn * TM + wn * 64 + j * 16 + lcol;
            #pragma unroll
            for (int r = 0; r < 4; ++r) {
                float s = acc[i][j][r];
                out[(size_t)(gr0 + r) * N_NODES + gc] = s > EPS ? s : 0.f;
                if (fabsf(s - EPS) < FIX_DELTA) {
                    u32 li = atomicAdd(&s_cnt, 1u);
                    u32 cell = (u32)((gr0 + r) * N_NODES + gc);
                    if (li < LCAP) s_list[li] = cell;
                    else { u32 g = atomicAdd(fcnt, 1u); if (g < FIX_CAP) flst[g] = cell; }
                }
            }
        }
    __syncthreads();
    u32 cnt = s_cnt < LCAP ? s_cnt : LCAP;
    if (tid == 0) s_base = atomicAdd(fcnt, cnt);
    __syncthreads();
    for (u32 t = tid; t < cnt; t += 256) {
        u32 g = s_base + t;
        if (g < FIX_CAP) flst[g] = s_list[t];
    }
}

// exact fp32 dot of rows i,j of Y (16-lane team)
__device__ __forceinline__ float dot_exact(const float* __restrict__ yf,
                                           u32 i, u32 j, int tl) {
    const float4v* ri = (const float4v*)(yf + (size_t)i * KTOT);
    const float4v* rj = (const float4v*)(yf + (size_t)j * KTOT);
    float4v p = {};
    #pragma unroll
    for (int q = 0; q < 8; ++q) p += ri[q * 16 + tl] * rj[q * 16 + tl];
    float s = p.x + p.y + p.z + p.w;
    #pragma unroll
    for (int o = 8; o >= 1; o >>= 1) s += __shfl_xor(s, o, 16);
    return s;
}

// K4: exact recompute of knife-edge sim cells
__global__ void fixup(const float* __restrict__ yf, const u32* __restrict__ fcnt,
                      const u32* __restrict__ flst, float* __restrict__ out) {
    u32 count = *fcnt; if (count > FIX_CAP) count = FIX_CAP;
    int team = (blockIdx.x * 256 + threadIdx.x) >> 4;
    int tl = threadIdx.x & 15;
    int nteams = gridDim.x * 16;
    for (u32 t = team; t < count; t += nteams) {
        u32 cell = flst[t];
        u32 i = cell >> 13, j = cell & 8191u;
        float s = dot_exact(yf, i, j, tl);
        if (tl == 0) out[cell] = s > EPS ? s : 0.f;
    }
}

// K5a: O(1) per unique edge cell — reuse gemm's stored sim (decision-exact post-fixup).
// sg==0 => s<=eps (proof: fixed cells exact; others s <= (eps-d)+d). a<=1 => no add.
// Knife-edge / a>1 / (sg==0, a~1) fall back to exact-dot list.
__global__ void edge_fast(const u32* __restrict__ hkey, const float* __restrict__ hval,
                          const u32* __restrict__ ucnt, const u32* __restrict__ ulist,
                          float* __restrict__ out,
                          u32* __restrict__ xcnt, u32* __restrict__ xlist) {
    u32 count = *ucnt;
    for (u32 t = blockIdx.x * 256 + threadIdx.x; t < count; t += gridDim.x * 256) {
        u32 h = ulist[t];
        u32 cell = hkey[h] - 1u;
        float a = hval[h];
        float sg = out[cell];
        bool hard = (a > 1.0f) ||
                    (sg > 0.f && fabsf(sg * a - EPS) < FIX_DELTA * a + 1e-6f) ||
                    (sg == 0.f && a > 0.97f);
        if (hard) {
            u32 g = atomicAdd(xcnt, 1u);
            if (g < XCAP) xlist[g] = h;
        } else if (sg > 0.f) {
            out[cell] = sg + ((sg * a > EPS) ? a : 0.f);
        } // sg==0, a<=0.97: provably no add, value stays 0
    }
}

// K5b: exact fallback for hard edge cells
__global__ void edge_exact(const float* __restrict__ yf, const u32* __restrict__ hkey,
                           const float* __restrict__ hval, const u32* __restrict__ xcnt,
                           const u32* __restrict__ xlist, float* __restrict__ out) {
    u32 count = *xcnt; if (count > XCAP) count = XCAP;
    int team = (blockIdx.x * 256 + threadIdx.x) >> 4;
    int tl = threadIdx.x & 15;
    int nteams = gridDim.x * 16;
    for (u32 t = team; t < count; t += nteams) {
        u32 h = xlist[t];
        u32 cell = hkey[h] - 1u;
        float a = hval[h];
        u32 i = cell >> 13, j = cell & 8191u;
        float s = dot_exact(yf, i, j, tl);
        if (tl == 0) {
            float v = s > EPS ? s : 0.f;
            if (s * a > EPS) v += a;
            out[cell] = v;
        }
    }
}

extern "C" void kernel_launch(void* const* d_in, const int* in_sizes, int n_in,
                              void* d_out, int out_size, void* d_ws, size_t ws_size,
                              hipStream_t stream) {
    const float* x  = (const float*)d_in[0];
    const int*   oi = (const int*)d_in[1];
    const float* ow = (const float*)d_in[2];
    const float* wp = (const float*)d_in[3];
    float* out = (float*)d_out;
    char* ws = (char*)d_ws;
    float* yf = (float*)(ws + OFF_YF);
    u16*   yb = (u16*)(ws + OFF_YB);
    u32*   fc = (u32*)(ws + OFF_CTR);
    u32*   uc = (u32*)(ws + OFF_CTR + 4);
    u32*   xc = (u32*)(ws + OFF_CTR + 8);
    u32*   hk = (u32*)(ws + OFF_HK);
    float* hv = (float*)(ws + OFF_HV);
    u32*   fl = (u32*)(ws + OFF_FL);
    u32*   ul = (u32*)(ws + OFF_UL);
    u32*   xl = (u32*)(ws + OFF_XL);

    prep_y<<<N_NODES / 4, 256, 0, stream>>>(x, wp, yf, yb);
    hipMemsetAsync(ws + MEMSET_OFF, 0, MEMSET_BYTES, stream);  // counters + hash
    edge_insert<<<NEDGE / 256, 256, 0, stream>>>(oi, ow, hk, hv, uc, ul);
    gemm_sim<<<dim3(N_NODES / TM, N_NODES / TM), 256, 0, stream>>>(yb, out, fc, fl);
    fixup<<<2048, 256, 0, stream>>>(yf, fc, fl, out);
    edge_fast<<<1024, 256, 0, stream>>>(hk, hv, uc, ul, out, xc, xl);
    edge_exact<<<256, 256, 0, stream>>>(yf, hk, hv, xc, xl, out);
}

// Round 7
// 495.840 us; speedup vs baseline: 5.0089x; 1.0611x over previous
//
#include <hip/hip_runtime.h>
#include <hip/hip_bf16.h>
#include <stdint.h>

// Graph_Refine: N=8192, D=128, E=262144, P=4, eps=0.3. fp32 I/O.
// R7: symmetric gram exploited properly — upper-tri grid (2080/4096 blocks),
// mirrored tile stored COALESCED via LDS transpose (b128 writes/reads,
// 132-float stride = conflict-free at the b128 floor). Pure streaming stores,
// no RMW (R5 lesson). Rest of pipeline = R6 (sim-reuse edge_fast + exact lists).
// Harness floor: ~243us of 0xAA poison fills (1GiB ws + 256MB out), untouchable.
#define N_NODES 8192
#define DIM     128
#define KTOT    512
#define NEDGE   262144
#define EPS     0.3f
#define FIX_DELTA 0.008f   // provable bf16-input dot bound: 2^-7*Sum|ab| <= 0.0078
#define FIX_CAP (1u << 19)
#define XCAP    (1u << 18)
#define LCAP    512
#define HASH_BITS 19
#define HASH_SLOTS (1u << HASH_BITS)

typedef unsigned int u32;
typedef unsigned short u16;
typedef __attribute__((ext_vector_type(8))) short short8;
typedef __attribute__((ext_vector_type(4))) float float4v;

// workspace layout (bytes)
#define OFF_YF  0u           // fp32 Y [8192][512] 16 MB
#define OFF_YB  16777216u    // bf16 Y  8 MB
#define OFF_CTR 25165824u    // counters: fc@0, uc@4, xc@8
#define OFF_HK  25166080u    // hash keys u32[2^19] 2 MB
#define OFF_HV  27263232u    // hash vals f32[2^19] 2 MB
#define OFF_FL  29360384u    // fixup list u32 2 MB
#define OFF_UL  31457536u    // unique list u32 1 MB
#define OFF_XL  32506112u    // exact-fallback list u32 1 MB
#define MEMSET_OFF OFF_CTR
#define MEMSET_BYTES (OFF_FL - OFF_CTR)

__device__ __forceinline__ u16 f2bf(float f) {  // RNE
    u32 b = __builtin_bit_cast(u32, f);
    b += 0x7fffu + ((b >> 16) & 1u);
    return (u16)(b >> 16);
}

// K1: reweight + L2-normalize per perspective; Y fp32 + bf16 (0.5 folds mean over P)
__global__ void prep_y(const float* __restrict__ x, const float* __restrict__ wp,
                       float* __restrict__ yf, u16* __restrict__ yb) {
    int node = blockIdx.x * 4 + (threadIdx.x >> 6);
    int lane = threadIdx.x & 63;
    float x0 = x[node * DIM + lane];
    float x1 = x[node * DIM + lane + 64];
    for (int p = 0; p < 4; ++p) {
        float v0 = x0 * wp[p * DIM + lane];
        float v1 = x1 * wp[p * DIM + lane + 64];
        float ss = v0 * v0 + v1 * v1;
        #pragma unroll
        for (int o = 1; o < 64; o <<= 1) ss += __shfl_xor(ss, o, 64);
        float scale = 0.5f / fmaxf(sqrtf(ss), 1e-12f);
        float y0 = v0 * scale, y1 = v1 * scale;
        int base = node * KTOT + p * DIM;
        yf[base + lane] = y0;       yf[base + lane + 64] = y1;
        yb[base + lane] = f2bf(y0); yb[base + lane + 64] = f2bf(y1);
    }
}

// K2: hash-aggregate duplicate edges + compact unique-slot list
__global__ void edge_insert(const int* __restrict__ idx, const float* __restrict__ w,
                            u32* __restrict__ hkey, float* __restrict__ hval,
                            u32* __restrict__ ucnt, u32* __restrict__ ulist) {
    int e = blockIdx.x * 256 + threadIdx.x;
    u32 cell = (u32)(idx[e] * N_NODES + idx[NEDGE + e]);
    float wv = w[e];
    u32 key = cell + 1u;
    u32 h = (cell * 2654435761u) >> (32 - HASH_BITS);
    while (true) {
        u32 old = atomicCAS(&hkey[h], 0u, key);
        if (old == 0u) { ulist[atomicAdd(ucnt, 1u)] = h; atomicAdd(&hval[h], wv); break; }
        if (old == key) { atomicAdd(&hval[h], wv); break; }
        h = (h + 1u) & (HASH_SLOTS - 1u);
    }
}

// K3: sim = Yb*Yb^T, upper-tri tiles; glds staging; direct + LDS-transposed stores.
#define TM  128
#define BK  64
#define TLD 132   // transpose buffer row stride (floats): b128 conflict-free, 16B aligned

__global__ __launch_bounds__(256)
void gemm_sim(const u16* __restrict__ yb, float* __restrict__ out,
              u32* __restrict__ fcnt, u32* __restrict__ flst) {
    int bm = blockIdx.y, bn = blockIdx.x;
    if (bm > bn) return;                       // symmetric: upper triangle only
    __shared__ __align__(16) char smem[64 * TLD * 4];   // 33792 B: As+Bs | tbuf
    u16* As = (u16*)smem;
    u16* Bs = As + TM * BK;
    float* tbuf = (float*)smem;                // used only after K-loop
    __shared__ u32 s_cnt, s_base;
    __shared__ u32 s_list[LCAP];
    int tid = threadIdx.x;
    int lane = tid & 63, wid = tid >> 6;
    int wm = wid >> 1, wn = wid & 1;
    if (tid == 0) s_cnt = 0;

    float4v acc[4][4] = {};
    const u16* arow = yb + (size_t)(bm * TM) * KTOT;
    const u16* brow = yb + (size_t)(bn * TM) * KTOT;

    for (int kt = 0; kt < KTOT / BK; ++kt) {
        __syncthreads();
        #pragma unroll
        for (int q = 0; q < 4; ++q) {
            int c = q * 256 + wid * 64 + lane;
            int row = c >> 3;
            int kg = (c & 7) ^ (row & 7);      // source-side XOR swizzle
            __builtin_amdgcn_global_load_lds(
                (const __attribute__((address_space(1))) void*)(const void*)(arow + (size_t)row * KTOT + kt * BK + kg * 8),
                (__attribute__((address_space(3))) void*)(void*)(As + (q * 256 + wid * 64) * 8),
                16, 0, 0);
            __builtin_amdgcn_global_load_lds(
                (const __attribute__((address_space(1))) void*)(const void*)(brow + (size_t)row * KTOT + kt * BK + kg * 8),
                (__attribute__((address_space(3))) void*)(void*)(Bs + (q * 256 + wid * 64) * 8),
                16, 0, 0);
        }
        __syncthreads();
        #pragma unroll
        for (int kk = 0; kk < 2; ++kk) {
            short8 af[4], bfr[4];
            int kg2 = kk * 4 + (lane >> 4);
            int mrow = wm * 64 + (lane & 15);
            int ncol = wn * 64 + (lane & 15);
            #pragma unroll
            for (int i = 0; i < 4; ++i) {
                int ra = mrow + i * 16, rb = ncol + i * 16;
                af[i]  = *(const short8*)&As[ra * BK + ((kg2 ^ (ra & 7)) * 8)];
                bfr[i] = *(const short8*)&Bs[rb * BK + ((kg2 ^ (rb & 7)) * 8)];
            }
            #pragma unroll
            for (int i = 0; i < 4; ++i)
                #pragma unroll
                for (int j = 0; j < 4; ++j)
                    acc[i][j] = __builtin_amdgcn_mfma_f32_16x16x32_bf16(
                        af[i], bfr[j], acc[i][j], 0, 0, 0);
        }
    }

    // epilogue A: direct tile stores + knife-edge flags (both orientations).
    // C/D layout: col=lane&15, row=(lane>>4)*4+reg [m89/m91]
    int quad = lane >> 4, lcol = lane & 15;
    #pragma unroll
    for (int i = 0; i < 4; ++i)
        #pragma unroll
        for (int j = 0; j < 4; ++j) {
            int gr0 = bm * TM + wm * 64 + i * 16 + quad * 4;
            int gc  = bn * TM + wn * 64 + j * 16 + lcol;
            #pragma unroll
            for (int r = 0; r < 4; ++r) {
                float s = acc[i][j][r];
                out[(size_t)(gr0 + r) * N_NODES + gc] = s > EPS ? s : 0.f;
                if (fabsf(s - EPS) < FIX_DELTA) {
                    u32 cellA = (u32)((gr0 + r) * N_NODES + gc);
                    u32 cellB = (u32)(gc * N_NODES + (gr0 + r));
                    u32 li = atomicAdd(&s_cnt, 2u);
                    if (li + 1 < LCAP) { s_list[li] = cellA; s_list[li + 1] = cellB; }
                    else {
                        u32 g = atomicAdd(fcnt, 2u);
                        if (g < FIX_CAP) flst[g] = cellA;
                        if (g + 1 < FIX_CAP) flst[g + 1] = cellB;
                    }
                }
            }
        }

    // epilogue B: mirrored tile via LDS transpose, two half-passes (wn==h active).
    // Lane's 4 regs = 4 consecutive rows -> contiguous after transpose -> b128.
    #pragma unroll
    for (int h = 0; h < 2; ++h) {
        __syncthreads();                       // LDS free (K-loop / prev pass done)
        if (wn == h) {
            #pragma unroll
            for (int i = 0; i < 4; ++i) {
                int Lr = wm * 64 + i * 16 + quad * 4;
                #pragma unroll
                for (int j = 0; j < 4; ++j) {
                    int Lc = j * 16 + lcol;    // col within this half
                    *(float4v*)&tbuf[Lc * TLD + Lr] = acc[i][j];
                }
            }
        }
        __syncthreads();
        #pragma unroll
        for (int v = 0; v < 8; ++v) {
            int chunk = v * 256 + tid;         // 2048 float4 chunks = 64x128 floats
            int row = chunk >> 5, c4 = chunk & 31;
            float4v t = *(const float4v*)&tbuf[row * TLD + c4 * 4];
            float4v o;
            #pragma unroll
            for (int r = 0; r < 4; ++r) o[r] = t[r] > EPS ? t[r] : 0.f;
            *(float4v*)&out[(size_t)(bn * TM + h * 64 + row) * N_NODES + bm * TM + c4 * 4] = o;
        }
    }

    __syncthreads();
    u32 cnt = s_cnt < LCAP ? s_cnt : LCAP;
    if (tid == 0) s_base = atomicAdd(fcnt, cnt);
    __syncthreads();
    for (u32 t = tid; t < cnt; t += 256) {
        u32 g = s_base + t;
        if (g < FIX_CAP) flst[g] = s_list[t];
    }
}

// exact fp32 dot of rows i,j of Y (16-lane team)
__device__ __forceinline__ float dot_exact(const float* __restrict__ yf,
                                           u32 i, u32 j, int tl) {
    const float4v* ri = (const float4v*)(yf + (size_t)i * KTOT);
    const float4v* rj = (const float4v*)(yf + (size_t)j * KTOT);
    float4v p = {};
    #pragma unroll
    for (int q = 0; q < 8; ++q) p += ri[q * 16 + tl] * rj[q * 16 + tl];
    float s = p.x + p.y + p.z + p.w;
    #pragma unroll
    for (int o = 8; o >= 1; o >>= 1) s += __shfl_xor(s, o, 16);
    return s;
}

// K4: exact recompute of knife-edge sim cells
__global__ void fixup(const float* __restrict__ yf, const u32* __restrict__ fcnt,
                      const u32* __restrict__ flst, float* __restrict__ out) {
    u32 count = *fcnt; if (count > FIX_CAP) count = FIX_CAP;
    int team = (blockIdx.x * 256 + threadIdx.x) >> 4;
    int tl = threadIdx.x & 15;
    int nteams = gridDim.x * 16;
    for (u32 t = team; t < count; t += nteams) {
        u32 cell = flst[t];
        u32 i = cell >> 13, j = cell & 8191u;
        float s = dot_exact(yf, i, j, tl);
        if (tl == 0) out[cell] = s > EPS ? s : 0.f;
    }
}

// K5a: O(1) per unique edge cell — reuse stored sim (decision-exact post-fixup)
__global__ void edge_fast(const u32* __restrict__ hkey, const float* __restrict__ hval,
                          const u32* __restrict__ ucnt, const u32* __restrict__ ulist,
                          float* __restrict__ out,
                          u32* __restrict__ xcnt, u32* __restrict__ xlist) {
    u32 count = *ucnt;
    for (u32 t = blockIdx.x * 256 + threadIdx.x; t < count; t += gridDim.x * 256) {
        u32 h = ulist[t];
        u32 cell = hkey[h] - 1u;
        float a = hval[h];
        float sg = out[cell];
        bool hard = (a > 1.0f) ||
                    (sg > 0.f && fabsf(sg * a - EPS) < FIX_DELTA * a + 1e-6f) ||
                    (sg == 0.f && a > 0.97f);
        if (hard) {
            u32 g = atomicAdd(xcnt, 1u);
            if (g < XCAP) xlist[g] = h;
        } else if (sg > 0.f) {
            out[cell] = sg + ((sg * a > EPS) ? a : 0.f);
        }
    }
}

// K5b: exact fallback for hard edge cells
__global__ void edge_exact(const float* __restrict__ yf, const u32* __restrict__ hkey,
                           const float* __restrict__ hval, const u32* __restrict__ xcnt,
                           const u32* __restrict__ xlist, float* __restrict__ out) {
    u32 count = *xcnt; if (count > XCAP) count = XCAP;
    int team = (blockIdx.x * 256 + threadIdx.x) >> 4;
    int tl = threadIdx.x & 15;
    int nteams = gridDim.x * 16;
    for (u32 t = team; t < count; t += nteams) {
        u32 h = xlist[t];
        u32 cell = hkey[h] - 1u;
        float a = hval[h];
        u32 i = cell >> 13, j = cell & 8191u;
        float s = dot_exact(yf, i, j, tl);
        if (tl == 0) {
            float v = s > EPS ? s : 0.f;
            if (s * a > EPS) v += a;
            out[cell] = v;
        }
    }
}

extern "C" void kernel_launch(void* const* d_in, const int* in_sizes, int n_in,
                              void* d_out, int out_size, void* d_ws, size_t ws_size,
                              hipStream_t stream) {
    const float* x  = (const float*)d_in[0];
    const int*   oi = (const int*)d_in[1];
    const float* ow = (const float*)d_in[2];
    const float* wp = (const float*)d_in[3];
    float* out = (float*)d_out;
    char* ws = (char*)d_ws;
    float* yf = (float*)(ws + OFF_YF);
    u16*   yb = (u16*)(ws + OFF_YB);
    u32*   fc = (u32*)(ws + OFF_CTR);
    u32*   uc = (u32*)(ws + OFF_CTR + 4);
    u32*   xc = (u32*)(ws + OFF_CTR + 8);
    u32*   hk = (u32*)(ws + OFF_HK);
    float* hv = (float*)(ws + OFF_HV);
    u32*   fl = (u32*)(ws + OFF_FL);
    u32*   ul = (u32*)(ws + OFF_UL);
    u32*   xl = (u32*)(ws + OFF_XL);

    prep_y<<<N_NODES / 4, 256, 0, stream>>>(x, wp, yf, yb);
    hipMemsetAsync(ws + MEMSET_OFF, 0, MEMSET_BYTES, stream);
    edge_insert<<<NEDGE / 256, 256, 0, stream>>>(oi, ow, hk, hv, uc, ul);
    gemm_sim<<<dim3(N_NODES / TM, N_NODES / TM), 256, 0, stream>>>(yb, out, fc, fl);
    fixup<<<2048, 256, 0, stream>>>(yf, fc, fl, out);
    edge_fast<<<1024, 256, 0, stream>>>(hk, hv, uc, ul, out, xc, xl);
    edge_exact<<<256, 256, 0, stream>>>(yf, hk, hv, xc, xl, out);
}